// Round 5
// baseline (46.948 us; speedup 1.0000x reference)
//
#include <hip/hip_runtime.h>

// RollingSignatureFeatures: B=64, S=2048, D=15, W=5, d=D+1=16, out=(B,S,272) fp32.
// level1[j]    = aug[s][j] - aug[max(s-4,0)][j]
// level2[i][j] = sum_{w=0..3} (aug[c(s+w-3)][i] - aug[c(s+w-4)][i]) * aug[c(s+w-4)][j]
// aug = [s/(S-1), features[s]], c() clamps at 0.
//
// R5: R4 fixed — __builtin_nontemporal_store requires a native vector type,
// not HIP_vector_type. Use ext_vector_type(4) float for the nt stores.

namespace {
constexpr int kB = 64;
constexpr int kS = 2048;
constexpr int kD = 15;
constexpr int kDD = 16;                // D + 1
constexpr int kW = 5;
constexpr int kTS = 64;                // output positions per block
constexpr int kRows = kTS + kW - 1;    // 68 staged aug rows
constexpr int kStride = 20;            // LDS row stride (floats)
constexpr int kOut = kDD + kDD * kDD;  // 272 floats per position

typedef float f32x4 __attribute__((ext_vector_type(4)));
}

__global__ __launch_bounds__(256, 8) void rollsig_kernel(const float* __restrict__ feat,
                                                         float* __restrict__ out) {
    const int tilesPerB = kS / kTS;  // 32
    const int b = blockIdx.x / tilesPerB;
    const int s0 = (blockIdx.x % tilesPerB) * kTS;

    __shared__ float lin[kRows * kStride];  // 5440 B

    const int tid = threadIdx.x;
    const float* fb = feat + (size_t)b * kS * kD;

    if (s0 != 0) {
        // Interior tile: rows s0-4 .. s0+63 = 1020 contiguous, 16B-aligned floats.
        if (tid < (kRows * kD) / 4) {  // 255 threads x float4
            const float4* src = (const float4*)(fb + (size_t)(s0 - (kW - 1)) * kD);
            float4 v = src[tid];
            const float vv[4] = {v.x, v.y, v.z, v.w};
            int i0 = tid * 4;
#pragma unroll
            for (int k = 0; k < 4; ++k) {
                int idx = i0 + k;
                int r = idx / kD;
                int c = idx - r * kD;
                lin[r * kStride + 1 + c] = vv[k];
            }
        }
    } else {
        // First tile of each batch row: clamp rows r<4 to s=0.
        for (int idx = tid; idx < kRows * kD; idx += 256) {
            int r = idx / kD;
            int c = idx - r * kD;
            int s = r - (kW - 1);
            if (s < 0) s = 0;
            lin[r * kStride + 1 + c] = fb[(size_t)s * kD + c];
        }
    }
    // Time channel: linspace(0,1,S)[s] = s / (S-1)
    if (tid < kRows) {
        int s = s0 + tid - (kW - 1);
        if (s < 0) s = 0;
        lin[tid * kStride] = (float)s * (1.0f / (float)(kS - 1));
    }
    __syncthreads();

    const int p = tid >> 2;  // position within tile, 0..63
    const int q = tid & 3;   // j-quad owner, 0..3
    const int s = s0 + p;

    float* ob = out + ((size_t)b * kS + s) * kOut;
    const float* lp = &lin[p * kStride];

    // This thread's j-quad of each window row (runtime q -> LDS address only)
    float4 l4[kW];
#pragma unroll
    for (int w = 0; w < kW; ++w) {
        l4[w] = *(const float4*)(lp + w * kStride + q * 4);
    }

    // level1
    f32x4 l1;
    l1.x = l4[4].x - l4[0].x;
    l1.y = l4[4].y - l4[0].y;
    l1.z = l4[4].z - l4[0].z;
    l1.w = l4[4].w - l4[0].w;
    __builtin_nontemporal_store(l1, (f32x4*)(ob + q * 4));

    // level2 streamed in 4 chunks of 4 rows; sequential fma accumulation
    // (w = 0..3 in order, acc starts at 0) to stay bit-exact vs reference.
#pragma unroll
    for (int ic = 0; ic < 4; ++ic) {
        float rr[kW][4];
#pragma unroll
        for (int w = 0; w < kW; ++w) {
            float4 t = *(const float4*)(lp + w * kStride + ic * 4);
            rr[w][0] = t.x;
            rr[w][1] = t.y;
            rr[w][2] = t.z;
            rr[w][3] = t.w;
        }
#pragma unroll
        for (int ii = 0; ii < 4; ++ii) {
            const int i = ic * 4 + ii;
            f32x4 a = {0.f, 0.f, 0.f, 0.f};
#pragma unroll
            for (int w = 0; w < 4; ++w) {
                float inc = rr[w + 1][ii] - rr[w][ii];
                a.x = fmaf(inc, l4[w].x, a.x);
                a.y = fmaf(inc, l4[w].y, a.y);
                a.z = fmaf(inc, l4[w].z, a.z);
                a.w = fmaf(inc, l4[w].w, a.w);
            }
            __builtin_nontemporal_store(a, (f32x4*)(ob + kDD + i * kDD + q * 4));
        }
    }
}

extern "C" void kernel_launch(void* const* d_in, const int* in_sizes, int n_in,
                              void* d_out, int out_size, void* d_ws, size_t ws_size,
                              hipStream_t stream) {
    const float* feat = (const float*)d_in[0];
    float* out = (float*)d_out;
    dim3 grid(kB * (kS / kTS));  // 2048 blocks
    rollsig_kernel<<<grid, 256, 0, stream>>>(feat, out);
}

// Round 7
// 28.660 us; speedup vs baseline: 1.6381x; 1.6381x over previous
//
#include <hip/hip_runtime.h>

// RollingSignatureFeatures: B=64, S=2048, D=15, W=5, d=D+1=16, out=(B,S,272) fp32.
// level1[j]    = aug[s][j] - aug[max(s-4,0)][j]
// level2[i][j] = sum_{w=0..3} (aug[c(s+w-3)][i] - aug[c(s+w-4)][i]) * aug[c(s+w-4)][j]
// aug = [s/(S-1), features[s]], c() clamps at 0.
//
// R6 (resubmit; prior round died to container failure): revert nt stores
// (R5: -64%, L2 write-combining is essential). Software-pipeline 2 tiles per
// block: tile-1 global loads issue before the first barrier so their HBM
// latency hides under tile-0 compute+stores.

namespace {
constexpr int kB = 64;
constexpr int kS = 2048;
constexpr int kD = 15;
constexpr int kDD = 16;                // D + 1
constexpr int kW = 5;
constexpr int kTS = 64;                // output positions per tile
constexpr int kRows = kTS + kW - 1;    // 68 staged aug rows
constexpr int kStride = 20;            // LDS row stride (floats)
constexpr int kOut = kDD + kDD * kDD;  // 272 floats per position
}

__device__ __forceinline__ void compute_tile(const float* __restrict__ lin,
                                             float* __restrict__ out,
                                             int b, int s0, int tid) {
    const int p = tid >> 2;  // position within tile
    const int q = tid & 3;   // j-quad owner
    const int s = s0 + p;

    float* ob = out + ((size_t)b * kS + s) * kOut;
    const float* lp = lin + p * kStride;

    float4 l4[kW];
#pragma unroll
    for (int w = 0; w < kW; ++w) {
        l4[w] = *(const float4*)(lp + w * kStride + q * 4);
    }

    float4 l1;
    l1.x = l4[4].x - l4[0].x;
    l1.y = l4[4].y - l4[0].y;
    l1.z = l4[4].z - l4[0].z;
    l1.w = l4[4].w - l4[0].w;
    *(float4*)(ob + q * 4) = l1;

#pragma unroll
    for (int ic = 0; ic < 4; ++ic) {
        float rr[kW][4];
#pragma unroll
        for (int w = 0; w < kW; ++w) {
            float4 t = *(const float4*)(lp + w * kStride + ic * 4);
            rr[w][0] = t.x;
            rr[w][1] = t.y;
            rr[w][2] = t.z;
            rr[w][3] = t.w;
        }
#pragma unroll
        for (int ii = 0; ii < 4; ++ii) {
            const int i = ic * 4 + ii;
            float4 a = make_float4(0.f, 0.f, 0.f, 0.f);
#pragma unroll
            for (int w = 0; w < 4; ++w) {
                float inc = rr[w + 1][ii] - rr[w][ii];
                a.x = fmaf(inc, l4[w].x, a.x);
                a.y = fmaf(inc, l4[w].y, a.y);
                a.z = fmaf(inc, l4[w].z, a.z);
                a.w = fmaf(inc, l4[w].w, a.w);
            }
            *(float4*)(ob + kDD + i * kDD + q * 4) = a;
        }
    }
}

__global__ __launch_bounds__(256, 8) void rollsig_kernel(const float* __restrict__ feat,
                                                         float* __restrict__ out) {
    const int pairsPerB = kS / (2 * kTS);  // 16
    const int b = blockIdx.x / pairsPerB;
    const int s0 = (blockIdx.x % pairsPerB) * (2 * kTS);  // tile0 at s0, tile1 at s0+64

    __shared__ float lin0[kRows * kStride];
    __shared__ float lin1[kRows * kStride];

    const int tid = threadIdx.x;
    const float* fb = feat + (size_t)b * kS * kD;

    // ---- Stage tile0 and issue tile1 loads (early, before first barrier) ----
    float4 v1 = make_float4(0.f, 0.f, 0.f, 0.f);
    const bool ld = tid < (kRows * kD) / 4;  // 255 threads x float4 = 1020 floats
    if (ld) {
        // tile1 rows start at s = s0+64-4; (s0+60)*15 is a multiple of 4 floats -> 16B aligned
        v1 = ((const float4*)(fb + (size_t)(s0 + kTS - (kW - 1)) * kD))[tid];
    }

    if (s0 != 0) {
        if (ld) {
            float4 v0 = ((const float4*)(fb + (size_t)(s0 - (kW - 1)) * kD))[tid];
            const float vv[4] = {v0.x, v0.y, v0.z, v0.w};
            int i0 = tid * 4;
#pragma unroll
            for (int k = 0; k < 4; ++k) {
                int idx = i0 + k;
                int r = idx / kD;
                int c = idx - r * kD;
                lin0[r * kStride + 1 + c] = vv[k];
            }
        }
    } else {
        for (int idx = tid; idx < kRows * kD; idx += 256) {
            int r = idx / kD;
            int c = idx - r * kD;
            int s = r - (kW - 1);
            if (s < 0) s = 0;
            lin0[r * kStride + 1 + c] = fb[(size_t)s * kD + c];
        }
    }
    // Time channels for both tiles
    if (tid < kRows) {
        int s = s0 + tid - (kW - 1);
        if (s < 0) s = 0;
        lin0[tid * kStride] = (float)s * (1.0f / (float)(kS - 1));
    } else if (tid >= 128 && tid < 128 + kRows) {
        int r = tid - 128;
        int s = s0 + kTS + r - (kW - 1);
        lin1[r * kStride] = (float)s * (1.0f / (float)(kS - 1));
    }
    __syncthreads();

    // ---- Compute + store tile0 (tile1 loads in flight) ----
    compute_tile(lin0, out, b, s0, tid);

    // ---- Write tile1 stage data, barrier, compute tile1 ----
    if (ld) {
        const float vv[4] = {v1.x, v1.y, v1.z, v1.w};
        int i0 = tid * 4;
#pragma unroll
        for (int k = 0; k < 4; ++k) {
            int idx = i0 + k;
            int r = idx / kD;
            int c = idx - r * kD;
            lin1[r * kStride + 1 + c] = vv[k];
        }
    }
    __syncthreads();

    compute_tile(lin1, out, b, s0 + kTS, tid);
}

extern "C" void kernel_launch(void* const* d_in, const int* in_sizes, int n_in,
                              void* d_out, int out_size, void* d_ws, size_t ws_size,
                              hipStream_t stream) {
    const float* feat = (const float*)d_in[0];
    float* out = (float*)d_out;
    dim3 grid(kB * (kS / (2 * kTS)));  // 1024 blocks, 2 tiles each
    rollsig_kernel<<<grid, 256, 0, stream>>>(feat, out);
}